// Round 14
// baseline (541.307 us; speedup 1.0000x reference)
//
#include <hip/hip_runtime.h>
#include <math.h>

#define HD 128
#define WD 128
#define HW (HD*WD)

typedef __attribute__((ext_vector_type(8))) short s16x8;     // 8 bf16 (4 VGPRs)
typedef __attribute__((ext_vector_type(4))) float f32x4;     // MFMA acc
typedef __attribute__((ext_vector_type(4))) unsigned int u32x4;
typedef __attribute__((ext_vector_type(2))) float f32x2;
typedef f32x2 __attribute__((aligned(4))) f32x2u;
typedef u32x4 __attribute__((aligned(4))) u32x4u;
typedef __attribute__((ext_vector_type(2))) unsigned int u32x2;
typedef u32x2 __attribute__((aligned(4))) u32x2u;

__device__ inline unsigned int pkbf(float a, float b) {
  unsigned int ua = __builtin_bit_cast(unsigned int, a);
  unsigned int ub = __builtin_bit_cast(unsigned int, b);
  ua = (ua + 0x7fffu + ((ua >> 16) & 1u)) >> 16;
  ub = (ub + 0x7fffu + ((ub >> 16) & 1u)) >> 16;
  return ua | (ub << 16);
}
__device__ __forceinline__ float blo(unsigned int u) {
  return __builtin_bit_cast(float, u << 16);
}
__device__ __forceinline__ float bhi(unsigned int u) {
  return __builtin_bit_cast(float, u & 0xffff0000u);
}

// ---------------------------------------------------------------------------
// Kernel 0a: Wcomb[9][128][128] bf16 for the main contraction.
// ---------------------------------------------------------------------------
__global__ __launch_bounds__(256) void k_prepw(
    const float* __restrict__ wr, const float* __restrict__ wi,
    unsigned short* __restrict__ wc) {
  int t = blockIdx.x * 256 + threadIdx.x;
  if (t >= 9 * 128 * 128) return;
  int c = t & 127;
  int r = (t >> 7) & 127;
  int k = t >> 14;
  float v;
  if (r < 64) v = (c < 64) ? wr[(r * 64 + c) * 9 + k] : -wi[(r * 64 + c - 64) * 9 + k];
  else {
    int r2 = r - 64;
    v = (c < 64) ? wi[(r2 * 64 + c) * 9 + k] : -wr[(r2 * 64 + c - 64) * 9 + k];
  }
  unsigned int u = __builtin_bit_cast(unsigned int, v);
  u = (u + 0x7fffu + ((u >> 16) & 1u)) >> 16;
  wc[t] = (unsigned short)u;
}

// ---------------------------------------------------------------------------
// Kernel 0b: W2[9 taps][32 rows][192 chans] bf16 for the off/mag GEMM.
// ---------------------------------------------------------------------------
__global__ __launch_bounds__(256) void k_prepw2(
    const float* __restrict__ w_off, const float* __restrict__ w_mag,
    unsigned short* __restrict__ w2) {
  int t = blockIdx.x * 256 + threadIdx.x;   // 9*32*192 = 55296 exactly
  int c = t % 192;
  int r = (t / 192) % 32;
  int k = t / (192 * 32);
  float v = 0.f;
  if (r < 18 && c < 128) v = w_off[((size_t)r * 128 + c) * 9 + k];
  else if (r >= 18 && r < 27 && c >= 128) v = w_mag[((size_t)(r - 18) * 64 + (c - 128)) * 9 + k];
  unsigned int u = __builtin_bit_cast(unsigned int, v);
  u = (u + 0x7fffu + ((u >> 16) & 1u)) >> 16;
  w2[t] = (unsigned short)u;
}

// ---------------------------------------------------------------------------
// Kernel 0c: coalesced X4 pack (32 groups/batch — L2-friendly round-12 layout).
//   grp 0..15: xr chans 4g..4g+3;  grp 16..31: xi chans.
// u32 index ((b*32+grp)*HW + pix)*2 + half; half0 = chans(0,1), half1 = (2,3).
// ---------------------------------------------------------------------------
__global__ __launch_bounds__(256) void k_prepx4(
    const float* __restrict__ xr, const float* __restrict__ xi,
    unsigned int* __restrict__ X4) {
  int b = blockIdx.x & 7;
  int idx = (blockIdx.x >> 3) * 256 + threadIdx.x;   // 0..131071
  int pix4 = idx & 4095;
  int grp = idx >> 12;                               // 0..31
  const float* src = (grp < 16) ? (xr + ((size_t)b * 64 + 4 * grp) * HW)
                                : (xi + ((size_t)b * 64 + 4 * (grp - 16)) * HW);
  const float* p = src + pix4 * 4;
  f32x4 c0 = *(const f32x4*)(p);
  f32x4 c1 = *(const f32x4*)(p + HW);
  f32x4 c2 = *(const f32x4*)(p + 2 * HW);
  f32x4 c3 = *(const f32x4*)(p + 3 * HW);
  u32x4 o0, o1;
#pragma unroll
  for (int j = 0; j < 2; ++j) {
    o0[2 * j] = pkbf(c0[j], c1[j]);
    o0[2 * j + 1] = pkbf(c2[j], c3[j]);
    o1[2 * j] = pkbf(c0[j + 2], c1[j + 2]);
    o1[2 * j + 1] = pkbf(c2[j + 2], c3[j + 2]);
  }
  unsigned int* dst = X4 + ((size_t)(b * 32 + grp) * HW + pix4 * 4) * 2;
  *(u32x4*)(dst) = o0;
  *(u32x4*)(dst + 4) = o1;
}

// ---------------------------------------------------------------------------
// helpers
// ---------------------------------------------------------------------------
__device__ __forceinline__ void tap_weights(
    int h, int w, int k, float dy, float dx, float m,
    float& W00, float& W01, float& W10, float& W11, int& o0, int& o1) {
  float py = (float)(h - 1 + k / 3) + dy;
  float px = (float)(w - 1 + k % 3) + dx;
  float y0f = floorf(py), x0f = floorf(px);
  float wy = py - y0f, wx = px - x0f;
  int y0 = (int)y0f, x0 = (int)x0f;

  int xl = x0 < 0 ? 0 : (x0 > WD - 2 ? WD - 2 : x0);
  float wl, wr;
  if (x0 < 0) { wl = (x0 == -1) ? wx : 0.f; wr = 0.f; }
  else if (x0 > WD - 2) { wl = 0.f; wr = (x0 == WD - 1) ? (1.f - wx) : 0.f; }
  else { wl = 1.f - wx; wr = wx; }

  int y1 = y0 + 1;
  int yc0 = y0 < 0 ? 0 : (y0 > HD - 1 ? HD - 1 : y0);
  int yc1 = y1 < 0 ? 0 : (y1 > HD - 1 ? HD - 1 : y1);
  float cy0 = ((unsigned)y0 < (unsigned)HD) ? (1.f - wy) * m : 0.f;
  float cy1 = ((unsigned)y1 < (unsigned)HD) ? wy * m : 0.f;

  W00 = cy0 * wl; W01 = cy0 * wr;
  W10 = cy1 * wl; W11 = cy1 * wr;
  o0 = yc0 * WD + xl;
  o1 = yc1 * WD + xl;
}

// gather 32 chans (4 slabs of 8) of one tap into swizzled LDS rows
__device__ __forceinline__ void gather_tap4(
    const unsigned int* xq, char* sbase, int swz, int cbase2,
    float W00, float W01, float W10, float W11, int o0, int o1) {
#pragma unroll
  for (int q = 0; q < 4; ++q) {
    const unsigned int* pg0 = xq + (size_t)(q * 2) * (2 * HW);
    const unsigned int* pg1 = pg0 + 2 * HW;
    u32x4 A0 = *(const u32x4u*)(pg0 + 2 * o0);
    u32x4 B0 = *(const u32x4u*)(pg0 + 2 * o1);
    u32x4 A1 = *(const u32x4u*)(pg1 + 2 * o0);
    u32x4 B1 = *(const u32x4u*)(pg1 + 2 * o1);
    float c0 = W00 * blo(A0[0]) + W01 * blo(A0[2]) + W10 * blo(B0[0]) + W11 * blo(B0[2]);
    float c1 = W00 * bhi(A0[0]) + W01 * bhi(A0[2]) + W10 * bhi(B0[0]) + W11 * bhi(B0[2]);
    float c2 = W00 * blo(A0[1]) + W01 * blo(A0[3]) + W10 * blo(B0[1]) + W11 * blo(B0[3]);
    float c3 = W00 * bhi(A0[1]) + W01 * bhi(A0[3]) + W10 * bhi(B0[1]) + W11 * bhi(B0[3]);
    float c4 = W00 * blo(A1[0]) + W01 * blo(A1[2]) + W10 * blo(B1[0]) + W11 * blo(B1[2]);
    float c5 = W00 * bhi(A1[0]) + W01 * bhi(A1[2]) + W10 * bhi(B1[0]) + W11 * bhi(B1[2]);
    float c6 = W00 * blo(A1[1]) + W01 * blo(A1[3]) + W10 * blo(B1[1]) + W11 * blo(B1[3]);
    float c7 = W00 * bhi(A1[1]) + W01 * bhi(A1[3]) + W10 * bhi(B1[1]) + W11 * bhi(B1[3]);
    u32x4 wv;
    wv[0] = pkbf(c0, c1);
    wv[1] = pkbf(c2, c3);
    wv[2] = pkbf(c4, c5);
    wv[3] = pkbf(c6, c7);
    *(u32x4*)(sbase + ((cbase2 + q * 16) ^ swz)) = wv;
  }
}

// load one 4-chan group (u32x2) for 192-space pair-index g2 (mag from 2 loads)
__device__ __forceinline__ u32x2 stage_pair(
    const unsigned int* __restrict__ X4, int b, int g2, int pix) {
  if (g2 < 32) {
    return *(const u32x2u*)&X4[((size_t)(b * 32 + g2) * HW + pix) * 2];
  }
  int gm = g2 - 32;
  u32x2 A = *(const u32x2u*)&X4[((size_t)(b * 32 + gm) * HW + pix) * 2];
  u32x2 B = *(const u32x2u*)&X4[((size_t)(b * 32 + 16 + gm) * HW + pix) * 2];
  u32x2 r;
  r.x = pkbf(sqrtf(blo(A.x) * blo(A.x) + blo(B.x) * blo(B.x)),
             sqrtf(bhi(A.x) * bhi(A.x) + bhi(B.x) * bhi(B.x)));
  r.y = pkbf(sqrtf(blo(A.y) * blo(A.y) + blo(B.y) * blo(B.y)),
             sqrtf(bhi(A.y) * bhi(A.y) + bhi(B.y) * bhi(B.y)));
  return r;
}

// ---------------------------------------------------------------------------
// Fused kernel.  Phase A: off/mag conv GEMM (barriered, shared staging) -> om.
// Phase B: BARRIER-FREE wave-autonomous taps — wave g owns pixels
// [16g,16g+16) x all 128 out rows (8 m-tiles); private 2x4KB LDS tap buffers;
// all LDS deps are same-wave (lgkmcnt only).  #pragma unroll 3 lets the
// scheduler overlap tap k+1 gathers with tap k MFMA.
// ---------------------------------------------------------------------------
__global__ __launch_bounds__(256, 4) void k_fused(
    const unsigned int* __restrict__ X4,
    const unsigned short* __restrict__ W2,
    const unsigned short* __restrict__ Wc,
    const float* __restrict__ b_real, const float* __restrict__ b_imag,
    float* __restrict__ out) {
  __shared__ __align__(16) char LB[33792 + 6912];
  float* om = (float*)(LB + 33792);                  // om[27][64]

  int blk = blockIdx.x;
  int b = blk & 7;                 // XCD-affine
  int rest = blk >> 3;
  int wt = rest & 1;
  int h = rest >> 1;
  int w0 = wt * 64;

  int tid = threadIdx.x;
  int lane = tid & 63;
  int g = tid >> 6;
  int l15 = lane & 15;
  int hi8 = (lane >> 4) * 8;

  // ================= phase A =================
  {
    int sub = tid & 3;
    int colm = tid >> 2;
    int jm = colm + 1;
    int wm = w0 + colm;

    f32x4 acc[2];
    acc[0] = (f32x4)(0.f);
    acc[1] = (f32x4)(0.f);

#pragma unroll 1
    for (int ty = 0; ty < 3; ++ty) {
      int y = h + ty - 1;
      if ((unsigned)y >= (unsigned)HD) continue;
      __syncthreads();
      int rb = y * WD;

#pragma unroll
      for (int i = 0; i < 12; ++i) {
        int g2 = sub + i * 4;                        // 0..47
        u32x2 pk2 = stage_pair(X4, b, g2, rb + wm);
        *(u32x2*)(LB + jm * 512 + ((8 * g2) ^ ((jm & 7) << 4))) = pk2;
      }
      if (tid < 96) {
        int j = (tid < 48) ? 0 : 65;
        int g2 = (tid < 48) ? tid : tid - 48;
        int wg = (j == 0) ? (w0 - 1) : (w0 + 64);
        u32x2 pk2;
        pk2.x = 0u; pk2.y = 0u;
        if ((unsigned)wg < (unsigned)WD) pk2 = stage_pair(X4, b, g2, rb + wg);
        *(u32x2*)(LB + j * 512 + ((8 * g2) ^ ((j & 7) << 4))) = pk2;
      }
      __syncthreads();

#pragma unroll
      for (int tx = 0; tx < 3; ++tx) {
        const unsigned short* wtap = W2 + (size_t)(ty * 3 + tx) * 32 * 192;
        int j = g * 16 + l15 + tx;
        const char* bcol = LB + j * 512;
        int xo2 = (j & 7) << 4;
#pragma unroll
        for (int s = 0; s < 6; ++s) {
          s16x8 bf = *(const s16x8*)(bcol + ((s * 64 + hi8 * 2) ^ xo2));
#pragma unroll
          for (int mt = 0; mt < 2; ++mt) {
            s16x8 af = *(const s16x8*)(wtap + (mt * 16 + l15) * 192 + s * 32 + hi8);
            acc[mt] = __builtin_amdgcn_mfma_f32_16x16x32_bf16(af, bf, acc[mt], 0, 0, 0);
          }
        }
      }
    }

    __syncthreads();
    int col = g * 16 + l15;
#pragma unroll
    for (int mt = 0; mt < 2; ++mt) {
#pragma unroll
      for (int r = 0; r < 4; ++r) {
        int row = mt * 16 + (lane >> 4) * 4 + r;
        float v = acc[mt][r];
        if (row < 18) om[row * 64 + col] = v;
        else if (row < 27) om[row * 64 + col] = 1.f / (1.f + expf(-v));
      }
    }
    __syncthreads();   // protect LB staging from phase-B overwrites
  }

  // ================= phase B (barrier-free) =================
  int pl = lane >> 2;              // pixel 0..15 within this wave's n-tile
  int cg = lane & 3;               // chan quarter this lane gathers
  int w = w0 + g * 16 + pl;        // this lane's gather pixel
  int pcol = g * 16 + pl;          // om column
  char* wbuf = LB + g * 8192;      // wave-private 2x4KB tap buffers
  int swzW = (pl & 7) << 4;
  int xoR = (l15 & 7) << 4;
  const unsigned int* xq = X4 + (size_t)(b * 32 + cg * 8) * (2 * HW);

  f32x4 acc[8];
#pragma unroll
  for (int t = 0; t < 8; ++t) acc[t] = (f32x4)(0.f);

#pragma unroll 3
  for (int k = 0; k < 9; ++k) {
    float dy = om[(2 * k) * 64 + pcol];
    float dx = om[(2 * k + 1) * 64 + pcol];
    float m  = om[(18 + k) * 64 + pcol];
    float W00, W01, W10, W11;
    int o0, o1;
    tap_weights(h, w, k, dy, dx, m, W00, W01, W10, W11, o0, o1);

    char* sb = wbuf + (k & 1) * 4096 + pl * 256;
    gather_tap4(xq, sb, swzW, cg * 64, W00, W01, W10, W11, o0, o1);

    const char* rbuf = wbuf + (k & 1) * 4096;
    __builtin_amdgcn_s_setprio(1);
#pragma unroll
    for (int s = 0; s < 4; ++s) {
      s16x8 bf = *(const s16x8*)(rbuf + l15 * 256 + ((s * 64 + hi8 * 2) ^ xoR));
      const unsigned short* wks = Wc + (size_t)k * 16384 + l15 * 128 + s * 32 + hi8;
#pragma unroll
      for (int mt = 0; mt < 8; ++mt) {
        s16x8 A = *(const s16x8*)(wks + mt * 2048);
        acc[mt] = __builtin_amdgcn_mfma_f32_16x16x32_bf16(A, bf, acc[mt], 0, 0, 0);
      }
    }
    __builtin_amdgcn_s_setprio(0);
  }

  // epilogue: rows <64 real, >=64 imag; col l15 = pixel g*16+l15
  f32x2* outp = (f32x2*)out;
  int pe = h * WD + w0 + g * 16 + l15;
#pragma unroll
  for (int mt = 0; mt < 4; ++mt) {
#pragma unroll
    for (int r = 0; r < 4; ++r) {
      int o = mt * 16 + (lane >> 4) * 4 + r;
      float br = b_real[o] - b_imag[o];
      f32x2 v;
      v.x = acc[mt][r] + br;
      v.y = acc[mt + 4][r] - br;
      __builtin_nontemporal_store(v, &outp[((size_t)(b * 64 + o)) * HW + pe]);
    }
  }
}

// ---------------------------------------------------------------------------
// Fallback path (ws too small for X4): f32 kernels (round-11 proven).
// ---------------------------------------------------------------------------
__global__ __launch_bounds__(256) void k_offmag_f32(
    const float* __restrict__ xr, const float* __restrict__ xi,
    const unsigned short* __restrict__ W2,
    float* __restrict__ off_o, float* __restrict__ mag_o) {
  __shared__ unsigned short S[66 * 256];
  int blk = blockIdx.x;
  int b = blk & 7;
  int rest = blk >> 3;
  int wt = rest & 1;
  int h = rest >> 1;
  int w0 = wt * 64;
  int tid = threadIdx.x;
  int lane = tid & 63;
  int g = tid >> 6;
  int l15 = lane & 15;
  int hi8 = (lane >> 4) * 8;
  const float* xrb = xr + (size_t)b * 64 * HW;
  const float* xib = xi + (size_t)b * 64 * HW;
  int sub = tid & 3;
  int colm = tid >> 2;
  int jm = colm + 1;
  int wm = w0 + colm;
  f32x4 acc[2];
  acc[0] = (f32x4)(0.f);
  acc[1] = (f32x4)(0.f);
#pragma unroll 1
  for (int ty = 0; ty < 3; ++ty) {
    int y = h + ty - 1;
    if ((unsigned)y >= (unsigned)HD) continue;
    __syncthreads();
    int rb = y * WD;
#pragma unroll
    for (int i = 0; i < 24; ++i) {
      int s = sub + i * 4;
      float v0, v1;
      if (s < 32) {
        const float* p = xrb + (size_t)(2 * s) * HW + rb + wm;
        v0 = p[0]; v1 = p[HW];
      } else if (s < 64) {
        const float* p = xib + (size_t)(2 * s - 64) * HW + rb + wm;
        v0 = p[0]; v1 = p[HW];
      } else {
        int c = 2 * s - 128;
        const float* pr = xrb + (size_t)c * HW + rb + wm;
        const float* pi = xib + (size_t)c * HW + rb + wm;
        float a0 = pr[0], a1 = pr[HW];
        float b0 = pi[0], b1 = pi[HW];
        v0 = sqrtf(a0 * a0 + b0 * b0);
        v1 = sqrtf(a1 * a1 + b1 * b1);
      }
      *(unsigned int*)((char*)S + jm * 512 + ((4 * s) ^ ((jm & 7) << 4))) = pkbf(v0, v1);
    }
    if (tid < 192) {
      int j = (tid < 96) ? 0 : 65;
      int s = (tid < 96) ? tid : tid - 96;
      int wg = (j == 0) ? (w0 - 1) : (w0 + 64);
      float v0 = 0.f, v1 = 0.f;
      if ((unsigned)wg < (unsigned)WD) {
        if (s < 32) {
          const float* p = xrb + (size_t)(2 * s) * HW + rb + wg;
          v0 = p[0]; v1 = p[HW];
        } else if (s < 64) {
          const float* p = xib + (size_t)(2 * s - 64) * HW + rb + wg;
          v0 = p[0]; v1 = p[HW];
        } else {
          int c = 2 * s - 128;
          const float* pr = xrb + (size_t)c * HW + rb + wg;
          const float* pi = xib + (size_t)c * HW + rb + wg;
          float a0 = pr[0], a1 = pr[HW];
          float b0 = pi[0], b1 = pi[HW];
          v0 = sqrtf(a0 * a0 + b0 * b0);
          v1 = sqrtf(a1 * a1 + b1 * b1);
        }
      }
      *(unsigned int*)((char*)S + j * 512 + ((4 * s) ^ ((j & 7) << 4))) = pkbf(v0, v1);
    }
    __syncthreads();
#pragma unroll
    for (int tx = 0; tx < 3; ++tx) {
      const unsigned short* wtap = W2 + (size_t)(ty * 3 + tx) * 32 * 192;
      int j = g * 16 + l15 + tx;
      const char* bcol = (const char*)S + j * 512;
      int xo = (j & 7) << 4;
#pragma unroll
      for (int s = 0; s < 6; ++s) {
        s16x8 bf = *(const s16x8*)(bcol + ((s * 64 + hi8 * 2) ^ xo));
#pragma unroll
        for (int mt = 0; mt < 2; ++mt) {
          s16x8 af = *(const s16x8*)(wtap + (mt * 16 + l15) * 192 + s * 32 + hi8);
          acc[mt] = __builtin_amdgcn_mfma_f32_16x16x32_bf16(af, bf, acc[mt], 0, 0, 0);
        }
      }
    }
  }
  int p = h * WD + w0 + g * 16 + l15;
#pragma unroll
  for (int mt = 0; mt < 2; ++mt) {
#pragma unroll
    for (int r = 0; r < 4; ++r) {
      int row = mt * 16 + (lane >> 4) * 4 + r;
      float v = acc[mt][r];
      if (row < 18) off_o[((size_t)(b * 18 + row)) * HW + p] = v;
      else if (row < 27) mag_o[((size_t)(b * 9 + row - 18)) * HW + p] = 1.f / (1.f + expf(-v));
    }
  }
}

__device__ __forceinline__ void gather_tap_f32(
    const float* xbase, char* sbase, int swz, int cbase2,
    float W00, float W01, float W10, float W11, int o0, int o1) {
#pragma unroll
  for (int q = 0; q < 4; ++q) {
    u32x4 wv;
#pragma unroll
    for (int j2 = 0; j2 < 4; ++j2) {
      const float* p0 = xbase + (size_t)(q * 8 + j2 * 2) * HW;
      const float* p1 = p0 + HW;
      f32x2u a0 = *(const f32x2u*)(p0 + o0);
      f32x2u b0 = *(const f32x2u*)(p0 + o1);
      f32x2u a1 = *(const f32x2u*)(p1 + o0);
      f32x2u b1 = *(const f32x2u*)(p1 + o1);
      float v0 = W00 * a0.x + W01 * a0.y + W10 * b0.x + W11 * b0.y;
      float v1 = W00 * a1.x + W01 * a1.y + W10 * b1.x + W11 * b1.y;
      wv[j2] = pkbf(v0, v1);
    }
    *(u32x4*)(sbase + ((cbase2 + q * 16) ^ swz)) = wv;
  }
}

__global__ __launch_bounds__(256, 4) void k_main_f32(
    const float* __restrict__ xr, const float* __restrict__ xi,
    const float* __restrict__ off_i, const float* __restrict__ mag_i,
    const unsigned short* __restrict__ Wc,
    const float* __restrict__ b_real, const float* __restrict__ b_imag,
    float* __restrict__ out) {
  __shared__ unsigned short S[2 * 64 * 128];
  int blk = blockIdx.x;
  int b = blk & 7;
  int rest = blk >> 3;
  int wt = rest & 1;
  int h = rest >> 1;
  int w0 = wt * 64;
  int tid = threadIdx.x;
  int lane = tid & 63;
  int g = tid >> 6;
  int w = w0 + lane;
  int l15 = lane & 15;
  int hi8 = (lane >> 4) * 8;
  int xo = l15 << 4;
  int swz = (lane & 15) << 4;
  const float* xrb = xr + (size_t)b * 64 * HW;
  const float* xib = xi + (size_t)b * 64 * HW;
  int cbase = g * 32;
  const float* xbase = (g < 2) ? (xrb + (size_t)cbase * HW)
                               : (xib + (size_t)(cbase - 64) * HW);
  int ppos = h * WD + w;
  char* sb0 = (char*)S + lane * 256;
  char* sb1 = (char*)S + 16384 + lane * 256;
  f32x4 accR[4], accI[4];
#pragma unroll
  for (int t = 0; t < 4; ++t) {
    accR[t] = (f32x4)(0.f);
    accI[t] = (f32x4)(0.f);
  }
#pragma unroll 1
  for (int ph = 0; ph < 5; ++ph) {
    int kA = ph * 2;
    int kB = kA + 1;
    bool two = (ph < 4);
    float dyA = off_i[((size_t)(b * 18 + 2 * kA)) * HW + ppos];
    float dxA = off_i[((size_t)(b * 18 + 2 * kA + 1)) * HW + ppos];
    float mA  = mag_i[((size_t)(b * 9 + kA)) * HW + ppos];
    float dyB = 0.f, dxB = 0.f, mB = 0.f;
    if (two) {
      dyB = off_i[((size_t)(b * 18 + 2 * kB)) * HW + ppos];
      dxB = off_i[((size_t)(b * 18 + 2 * kB + 1)) * HW + ppos];
      mB  = mag_i[((size_t)(b * 9 + kB)) * HW + ppos];
    }
    __syncthreads();
    {
      float W00, W01, W10, W11; int o0, o1;
      tap_weights(h, w, kA, dyA, dxA, mA, W00, W01, W10, W11, o0, o1);
      gather_tap_f32(xbase, sb0, swz, cbase * 2, W00, W01, W10, W11, o0, o1);
    }
    if (two) {
      float W00, W01, W10, W11; int o0, o1;
      tap_weights(h, w, kB, dyB, dxB, mB, W00, W01, W10, W11, o0, o1);
      gather_tap_f32(xbase, sb1, swz, cbase * 2, W00, W01, W10, W11, o0, o1);
    }
    __syncthreads();
    {
      const unsigned short* wa = Wc + (size_t)kA * 16384 + (g * 16 + l15) * 128 + hi8;
      s16x8 aR[4], aI[4];
#pragma unroll
      for (int s = 0; s < 4; ++s) {
        aR[s] = *(const s16x8*)(wa + s * 32);
        aI[s] = *(const s16x8*)(wa + 64 * 128 + s * 32);
      }
#pragma unroll
      for (int t = 0; t < 4; ++t) {
        const char* brow = (const char*)S + (t * 16 + l15) * 256;
#pragma unroll
        for (int s = 0; s < 4; ++s) {
          s16x8 bf = *(const s16x8*)(brow + ((s * 64 + (hi8 << 1)) ^ xo));
          accR[t] = __builtin_amdgcn_mfma_f32_16x16x32_bf16(aR[s], bf, accR[t], 0, 0, 0);
          accI[t] = __builtin_amdgcn_mfma_f32_16x16x32_bf16(aI[s], bf, accI[t], 0, 0, 0);
        }
      }
    }
    if (two) {
      const unsigned short* wa = Wc + (size_t)kB * 16384 + (g * 16 + l15) * 128 + hi8;
      s16x8 aR[4], aI[4];
#pragma unroll
      for (int s = 0; s < 4; ++s) {
        aR[s] = *(const s16x8*)(wa + s * 32);
        aI[s] = *(const s16x8*)(wa + 64 * 128 + s * 32);
      }
#pragma unroll
      for (int t = 0; t < 4; ++t) {
        const char* brow = (const char*)S + 16384 + (t * 16 + l15) * 256;
#pragma unroll
        for (int s = 0; s < 4; ++s) {
          s16x8 bf = *(const s16x8*)(brow + ((s * 64 + (hi8 << 1)) ^ xo));
          accR[t] = __builtin_amdgcn_mfma_f32_16x16x32_bf16(aR[s], bf, accR[t], 0, 0, 0);
          accI[t] = __builtin_amdgcn_mfma_f32_16x16x32_bf16(aI[s], bf, accI[t], 0, 0, 0);
        }
      }
    }
  }
  f32x2* outp = (f32x2*)out;
#pragma unroll
  for (int r = 0; r < 4; ++r) {
    int o = g * 16 + (lane >> 4) * 4 + r;
    float br = b_real[o] - b_imag[o];
#pragma unroll
    for (int t = 0; t < 4; ++t) {
      int pe = h * WD + w0 + t * 16 + l15;
      f32x2 v;
      v.x = accR[t][r] + br;
      v.y = accI[t][r] - br;
      __builtin_nontemporal_store(v, &outp[((size_t)(b * 64 + o)) * HW + pe]);
    }
  }
}

// ---------------------------------------------------------------------------
extern "C" void kernel_launch(void* const* d_in, const int* in_sizes, int n_in,
                              void* d_out, int out_size, void* d_ws, size_t ws_size,
                              hipStream_t stream) {
  const float* xr     = (const float*)d_in[0];
  const float* xi     = (const float*)d_in[1];
  const float* w_off  = (const float*)d_in[2];
  const float* w_mag  = (const float*)d_in[3];
  const float* w_real = (const float*)d_in[4];
  const float* w_imag = (const float*)d_in[5];
  const float* b_real = (const float*)d_in[6];
  const float* b_imag = (const float*)d_in[7];
  float* out = (float*)d_out;

  unsigned short* Wc = (unsigned short*)d_ws;        // 147456 bf16
  unsigned short* W2 = Wc + 147456;                  // 55296 bf16
  char* rest = (char*)(W2 + 55296);
  unsigned int* X4 = (unsigned int*)rest;            // 8*32*HW*2 = 8388608 u32
  float* off_ws = (float*)rest;                      // fallback union
  float* mag_ws = off_ws + 2359296;
  const size_t need = (rest - (char*)d_ws) + (size_t)8388608 * 4;
  bool use_x4 = ws_size >= need;

  hipLaunchKernelGGL(k_prepw, dim3(576), dim3(256), 0, stream,
                     w_real, w_imag, Wc);
  hipLaunchKernelGGL(k_prepw2, dim3(216), dim3(256), 0, stream,
                     w_off, w_mag, W2);
  if (use_x4) {
    hipLaunchKernelGGL(k_prepx4, dim3(4096), dim3(256), 0, stream, xr, xi, X4);
    hipLaunchKernelGGL(k_fused, dim3(2048), dim3(256), 0, stream,
                       X4, W2, Wc, b_real, b_imag, out);
  } else {
    hipLaunchKernelGGL(k_offmag_f32, dim3(2048), dim3(256), 0, stream,
                       xr, xi, W2, off_ws, mag_ws);
    hipLaunchKernelGGL(k_main_f32, dim3(2048), dim3(256), 0, stream,
                       xr, xi, off_ws, mag_ws, Wc, b_real, b_imag, out);
  }
}

// Round 15
// 329.518 us; speedup vs baseline: 1.6427x; 1.6427x over previous
//
#include <hip/hip_runtime.h>
#include <math.h>

#define HD 128
#define WD 128
#define HW (HD*WD)

typedef __attribute__((ext_vector_type(8))) short s16x8;     // 8 bf16 (4 VGPRs)
typedef __attribute__((ext_vector_type(4))) float f32x4;     // MFMA acc
typedef __attribute__((ext_vector_type(4))) unsigned int u32x4;
typedef __attribute__((ext_vector_type(2))) float f32x2;
typedef f32x2 __attribute__((aligned(4))) f32x2u;
typedef u32x4 __attribute__((aligned(4))) u32x4u;
typedef __attribute__((ext_vector_type(2))) unsigned int u32x2;
typedef u32x2 __attribute__((aligned(4))) u32x2u;

__device__ inline unsigned int pkbf(float a, float b) {
  unsigned int ua = __builtin_bit_cast(unsigned int, a);
  unsigned int ub = __builtin_bit_cast(unsigned int, b);
  ua = (ua + 0x7fffu + ((ua >> 16) & 1u)) >> 16;
  ub = (ub + 0x7fffu + ((ub >> 16) & 1u)) >> 16;
  return ua | (ub << 16);
}
__device__ __forceinline__ float blo(unsigned int u) {
  return __builtin_bit_cast(float, u << 16);
}
__device__ __forceinline__ float bhi(unsigned int u) {
  return __builtin_bit_cast(float, u & 0xffff0000u);
}

// ---------------------------------------------------------------------------
// Kernel 0a: Wcomb[9][128][128] bf16 for the main contraction.
// ---------------------------------------------------------------------------
__global__ __launch_bounds__(256) void k_prepw(
    const float* __restrict__ wr, const float* __restrict__ wi,
    unsigned short* __restrict__ wc) {
  int t = blockIdx.x * 256 + threadIdx.x;
  if (t >= 9 * 128 * 128) return;
  int c = t & 127;
  int r = (t >> 7) & 127;
  int k = t >> 14;
  float v;
  if (r < 64) v = (c < 64) ? wr[(r * 64 + c) * 9 + k] : -wi[(r * 64 + c - 64) * 9 + k];
  else {
    int r2 = r - 64;
    v = (c < 64) ? wi[(r2 * 64 + c) * 9 + k] : -wr[(r2 * 64 + c - 64) * 9 + k];
  }
  unsigned int u = __builtin_bit_cast(unsigned int, v);
  u = (u + 0x7fffu + ((u >> 16) & 1u)) >> 16;
  wc[t] = (unsigned short)u;
}

// ---------------------------------------------------------------------------
// Kernel 0b: W2[9 taps][32 rows][192 chans] bf16 for the off/mag GEMM.
// ---------------------------------------------------------------------------
__global__ __launch_bounds__(256) void k_prepw2(
    const float* __restrict__ w_off, const float* __restrict__ w_mag,
    unsigned short* __restrict__ w2) {
  int t = blockIdx.x * 256 + threadIdx.x;   // 9*32*192 = 55296 exactly
  int c = t % 192;
  int r = (t / 192) % 32;
  int k = t / (192 * 32);
  float v = 0.f;
  if (r < 18 && c < 128) v = w_off[((size_t)r * 128 + c) * 9 + k];
  else if (r >= 18 && r < 27 && c >= 128) v = w_mag[((size_t)(r - 18) * 64 + (c - 128)) * 9 + k];
  unsigned int u = __builtin_bit_cast(unsigned int, v);
  u = (u + 0x7fffu + ((u >> 16) & 1u)) >> 16;
  w2[t] = (unsigned short)u;
}

// ---------------------------------------------------------------------------
// Kernel 0c: coalesced X4 pack (32 groups/batch).
//   grp 0..15: xr chans 4g..4g+3;  grp 16..31: xi chans.
// u32 index ((b*32+grp)*HW + pix)*2 + half; half0 = chans(0,1), half1 = (2,3).
// ---------------------------------------------------------------------------
__global__ __launch_bounds__(256) void k_prepx4(
    const float* __restrict__ xr, const float* __restrict__ xi,
    unsigned int* __restrict__ X4) {
  int b = blockIdx.x & 7;
  int idx = (blockIdx.x >> 3) * 256 + threadIdx.x;   // 0..131071
  int pix4 = idx & 4095;
  int grp = idx >> 12;                               // 0..31
  const float* src = (grp < 16) ? (xr + ((size_t)b * 64 + 4 * grp) * HW)
                                : (xi + ((size_t)b * 64 + 4 * (grp - 16)) * HW);
  const float* p = src + pix4 * 4;
  f32x4 c0 = *(const f32x4*)(p);
  f32x4 c1 = *(const f32x4*)(p + HW);
  f32x4 c2 = *(const f32x4*)(p + 2 * HW);
  f32x4 c3 = *(const f32x4*)(p + 3 * HW);
  u32x4 o0, o1;
#pragma unroll
  for (int j = 0; j < 2; ++j) {
    o0[2 * j] = pkbf(c0[j], c1[j]);
    o0[2 * j + 1] = pkbf(c2[j], c3[j]);
    o1[2 * j] = pkbf(c0[j + 2], c1[j + 2]);
    o1[2 * j + 1] = pkbf(c2[j + 2], c3[j + 2]);
  }
  unsigned int* dst = X4 + ((size_t)(b * 32 + grp) * HW + pix4 * 4) * 2;
  *(u32x4*)(dst) = o0;
  *(u32x4*)(dst + 4) = o1;
}

// ---------------------------------------------------------------------------
// helpers
// ---------------------------------------------------------------------------
__device__ __forceinline__ void tap_weights(
    int h, int w, int k, float dy, float dx, float m,
    float& W00, float& W01, float& W10, float& W11, int& o0, int& o1) {
  float py = (float)(h - 1 + k / 3) + dy;
  float px = (float)(w - 1 + k % 3) + dx;
  float y0f = floorf(py), x0f = floorf(px);
  float wy = py - y0f, wx = px - x0f;
  int y0 = (int)y0f, x0 = (int)x0f;

  int xl = x0 < 0 ? 0 : (x0 > WD - 2 ? WD - 2 : x0);
  float wl, wr;
  if (x0 < 0) { wl = (x0 == -1) ? wx : 0.f; wr = 0.f; }
  else if (x0 > WD - 2) { wl = 0.f; wr = (x0 == WD - 1) ? (1.f - wx) : 0.f; }
  else { wl = 1.f - wx; wr = wx; }

  int y1 = y0 + 1;
  int yc0 = y0 < 0 ? 0 : (y0 > HD - 1 ? HD - 1 : y0);
  int yc1 = y1 < 0 ? 0 : (y1 > HD - 1 ? HD - 1 : y1);
  float cy0 = ((unsigned)y0 < (unsigned)HD) ? (1.f - wy) * m : 0.f;
  float cy1 = ((unsigned)y1 < (unsigned)HD) ? wy * m : 0.f;

  W00 = cy0 * wl; W01 = cy0 * wr;
  W10 = cy1 * wl; W11 = cy1 * wr;
  o0 = yc0 * WD + xl;
  o1 = yc1 * WD + xl;
}

// gather 32 chans (4 slabs of 8) of one tap into swizzled LDS rows
__device__ __forceinline__ void gather_tap4(
    const unsigned int* xq, char* sbase, int swz, int cbase2,
    float W00, float W01, float W10, float W11, int o0, int o1) {
#pragma unroll
  for (int q = 0; q < 4; ++q) {
    const unsigned int* pg0 = xq + (size_t)(q * 2) * (2 * HW);
    const unsigned int* pg1 = pg0 + 2 * HW;
    u32x4 A0 = *(const u32x4u*)(pg0 + 2 * o0);
    u32x4 B0 = *(const u32x4u*)(pg0 + 2 * o1);
    u32x4 A1 = *(const u32x4u*)(pg1 + 2 * o0);
    u32x4 B1 = *(const u32x4u*)(pg1 + 2 * o1);
    float c0 = W00 * blo(A0[0]) + W01 * blo(A0[2]) + W10 * blo(B0[0]) + W11 * blo(B0[2]);
    float c1 = W00 * bhi(A0[0]) + W01 * bhi(A0[2]) + W10 * bhi(B0[0]) + W11 * bhi(B0[2]);
    float c2 = W00 * blo(A0[1]) + W01 * blo(A0[3]) + W10 * blo(B0[1]) + W11 * blo(B0[3]);
    float c3 = W00 * bhi(A0[1]) + W01 * bhi(A0[3]) + W10 * bhi(B0[1]) + W11 * bhi(B0[3]);
    float c4 = W00 * blo(A1[0]) + W01 * blo(A1[2]) + W10 * blo(B1[0]) + W11 * blo(B1[2]);
    float c5 = W00 * bhi(A1[0]) + W01 * bhi(A1[2]) + W10 * bhi(B1[0]) + W11 * bhi(B1[2]);
    float c6 = W00 * blo(A1[1]) + W01 * blo(A1[3]) + W10 * blo(B1[1]) + W11 * blo(B1[3]);
    float c7 = W00 * bhi(A1[1]) + W01 * bhi(A1[3]) + W10 * bhi(B1[1]) + W11 * bhi(B1[3]);
    u32x4 wv;
    wv[0] = pkbf(c0, c1);
    wv[1] = pkbf(c2, c3);
    wv[2] = pkbf(c4, c5);
    wv[3] = pkbf(c6, c7);
    *(u32x4*)(sbase + ((cbase2 + q * 16) ^ swz)) = wv;
  }
}

__device__ __forceinline__ void mfma_tap(
    const unsigned short* Wc, int k, const char* stap,
    int g, int l15, int hi8, int xo, f32x4* accR, f32x4* accI) {
  const unsigned short* wa = Wc + (size_t)k * 16384 + (g * 16 + l15) * 128 + hi8;
  s16x8 aR[4], aI[4];
#pragma unroll
  for (int s = 0; s < 4; ++s) {
    aR[s] = *(const s16x8*)(wa + s * 32);
    aI[s] = *(const s16x8*)(wa + 64 * 128 + s * 32);
  }
  __builtin_amdgcn_s_setprio(1);
#pragma unroll
  for (int t = 0; t < 4; ++t) {
    const char* brow = stap + (t * 16 + l15) * 256;
#pragma unroll
    for (int s = 0; s < 4; ++s) {
      s16x8 bf = *(const s16x8*)(brow + ((s * 64 + (hi8 << 1)) ^ xo));
      accR[t] = __builtin_amdgcn_mfma_f32_16x16x32_bf16(aR[s], bf, accR[t], 0, 0, 0);
      accI[t] = __builtin_amdgcn_mfma_f32_16x16x32_bf16(aI[s], bf, accI[t], 0, 0, 0);
    }
  }
  __builtin_amdgcn_s_setprio(0);
}

// load one 4-chan group (u32x2) for 192-space pair-index g2 (mag on the fly)
__device__ __forceinline__ u32x2 stage_pair(
    const unsigned int* __restrict__ X4, int b, int g2, int pix) {
  if (g2 < 32) {
    return *(const u32x2u*)&X4[((size_t)(b * 32 + g2) * HW + pix) * 2];
  }
  int gm = g2 - 32;
  u32x2 A = *(const u32x2u*)&X4[((size_t)(b * 32 + gm) * HW + pix) * 2];
  u32x2 B = *(const u32x2u*)&X4[((size_t)(b * 32 + 16 + gm) * HW + pix) * 2];
  u32x2 r;
  r.x = pkbf(sqrtf(blo(A.x) * blo(A.x) + blo(B.x) * blo(B.x)),
             sqrtf(bhi(A.x) * bhi(A.x) + bhi(B.x) * bhi(B.x)));
  r.y = pkbf(sqrtf(blo(A.y) * blo(A.y) + blo(B.y) * blo(B.y)),
             sqrtf(bhi(A.y) * bhi(A.y) + bhi(B.y) * bhi(B.y)));
  return r;
}

// ---------------------------------------------------------------------------
// Fused kernel (round-12 proven structure, LDS shrunk 40960 -> 32768 for
// 5 blocks/CU).  Phase A staging re-laid as [48 groups][66 cols] u32x2
// (stride 528B, 25344B); om at LB+25344 then copied to 27 regs/thread;
// phase-B loop fully unrolled so omr[] indices are static.
// ---------------------------------------------------------------------------
__global__ __launch_bounds__(256, 5) void k_fused(
    const unsigned int* __restrict__ X4,
    const unsigned short* __restrict__ W2,
    const unsigned short* __restrict__ Wc,
    const float* __restrict__ b_real, const float* __restrict__ b_imag,
    float* __restrict__ out) {
  __shared__ __align__(16) char LB[32768];
  float* om = (float*)(LB + 25344);                  // om[27][64], 6912B

  int blk = blockIdx.x;
  int b = blk & 7;                 // XCD-affine
  int rest = blk >> 3;
  int wt = rest & 1;
  int h = rest >> 1;
  int w0 = wt * 64;

  int tid = threadIdx.x;
  int lane = tid & 63;
  int g = tid >> 6;
  int l15 = lane & 15;
  int hi8 = (lane >> 4) * 8;

  // ================= phase A =================
  {
    int sub = tid & 3;
    int colm = tid >> 2;
    int jm = colm + 1;
    int wm = w0 + colm;

    f32x4 acc[2];
    acc[0] = (f32x4)(0.f);
    acc[1] = (f32x4)(0.f);

#pragma unroll 1
    for (int ty = 0; ty < 3; ++ty) {
      int y = h + ty - 1;
      if ((unsigned)y >= (unsigned)HD) continue;
      __syncthreads();
      int rb = y * WD;

#pragma unroll
      for (int i = 0; i < 12; ++i) {
        int g2 = sub + i * 4;                        // 0..47
        u32x2 pk2 = stage_pair(X4, b, g2, rb + wm);
        *(u32x2*)(LB + g2 * 528 + jm * 8) = pk2;
      }
      if (tid < 96) {
        int j = (tid < 48) ? 0 : 65;
        int g2 = (tid < 48) ? tid : tid - 48;
        int wg = (j == 0) ? (w0 - 1) : (w0 + 64);
        u32x2 pk2;
        pk2.x = 0u; pk2.y = 0u;
        if ((unsigned)wg < (unsigned)WD) pk2 = stage_pair(X4, b, g2, rb + wg);
        *(u32x2*)(LB + g2 * 528 + j * 8) = pk2;
      }
      __syncthreads();

#pragma unroll
      for (int tx = 0; tx < 3; ++tx) {
        const unsigned short* wtap = W2 + (size_t)(ty * 3 + tx) * 32 * 192;
        int j = g * 16 + l15 + tx;
#pragma unroll
        for (int s = 0; s < 6; ++s) {
          int g2a = s * 8 + (lane >> 4) * 2;
          u32x2 lo = *(const u32x2u*)(LB + g2a * 528 + j * 8);
          u32x2 hi2 = *(const u32x2u*)(LB + (g2a + 1) * 528 + j * 8);
          u32x4 comb;
          comb[0] = lo.x; comb[1] = lo.y; comb[2] = hi2.x; comb[3] = hi2.y;
          s16x8 bf = __builtin_bit_cast(s16x8, comb);
#pragma unroll
          for (int mt = 0; mt < 2; ++mt) {
            s16x8 af = *(const s16x8*)(wtap + (mt * 16 + l15) * 192 + s * 32 + hi8);
            acc[mt] = __builtin_amdgcn_mfma_f32_16x16x32_bf16(af, bf, acc[mt], 0, 0, 0);
          }
        }
      }
    }

    __syncthreads();   // staging reads done; om region may now be written
    int col = g * 16 + l15;
#pragma unroll
    for (int mt = 0; mt < 2; ++mt) {
#pragma unroll
      for (int r = 0; r < 4; ++r) {
        int row = mt * 16 + (lane >> 4) * 4 + r;
        float v = acc[mt][r];
        if (row < 18) om[row * 64 + col] = v;
        else if (row < 27) om[row * 64 + col] = 1.f / (1.f + expf(-v));
      }
    }
    __syncthreads();
  }

  // copy this thread's pixel's 27 off/mag values to registers (om region is
  // inside phase-B buffer 1 and will be overwritten by the first gather)
  float omr[27];
#pragma unroll
  for (int r = 0; r < 27; ++r) omr[r] = om[r * 64 + lane];
  __syncthreads();

  // ================= phase B (round-12 structure, om from registers) =======
  int w = w0 + lane;
  int xo = l15 << 4;
  int swz = (lane & 15) << 4;
  int cbase = g * 32;
  const unsigned int* xq = X4 + (size_t)(b * 32 + g * 8) * (2 * HW);
  char* sb0 = LB + lane * 256;
  char* sb1 = LB + 16384 + lane * 256;

  f32x4 accR[4], accI[4];
#pragma unroll
  for (int t = 0; t < 4; ++t) {
    accR[t] = (f32x4)(0.f);
    accI[t] = (f32x4)(0.f);
  }

#pragma unroll
  for (int ph = 0; ph < 5; ++ph) {
    int kA = ph * 2;
    int kB = kA + 1;
    bool two = (ph < 4);

    float dyA = omr[4 * ph];
    float dxA = omr[4 * ph + 1];
    float mA  = omr[18 + 2 * ph];
    float dyB = 0.f, dxB = 0.f, mB = 0.f;
    if (two) {
      dyB = omr[4 * ph + 2];
      dxB = omr[4 * ph + 3];
      mB  = omr[18 + 2 * ph + 1];
    }

    __syncthreads();   // prev MFMA phase done reading tap buffers

    {
      float W00, W01, W10, W11; int o0, o1;
      tap_weights(h, w, kA, dyA, dxA, mA, W00, W01, W10, W11, o0, o1);
      gather_tap4(xq, sb0, swz, cbase * 2, W00, W01, W10, W11, o0, o1);
    }
    if (two) {
      float W00, W01, W10, W11; int o0, o1;
      tap_weights(h, w, kB, dyB, dxB, mB, W00, W01, W10, W11, o0, o1);
      gather_tap4(xq, sb1, swz, cbase * 2, W00, W01, W10, W11, o0, o1);
    }
    __syncthreads();

    mfma_tap(Wc, kA, LB, g, l15, hi8, xo, accR, accI);
    if (two)
      mfma_tap(Wc, kB, LB + 16384, g, l15, hi8, xo, accR, accI);
  }

  // epilogue: bias + coalesced nontemporal f32x2 stores
  f32x2* outp = (f32x2*)out;
#pragma unroll
  for (int r = 0; r < 4; ++r) {
    int o = g * 16 + (lane >> 4) * 4 + r;
    float br = b_real[o] - b_imag[o];
#pragma unroll
    for (int t = 0; t < 4; ++t) {
      int pe = h * WD + w0 + t * 16 + l15;
      f32x2 v;
      v.x = accR[t][r] + br;
      v.y = accI[t][r] - br;
      __builtin_nontemporal_store(v, &outp[((size_t)(b * 64 + o)) * HW + pe]);
    }
  }
}

// ---------------------------------------------------------------------------
// Fallback path (ws too small for X4): f32 kernels (round-11 proven).
// ---------------------------------------------------------------------------
__global__ __launch_bounds__(256) void k_offmag_f32(
    const float* __restrict__ xr, const float* __restrict__ xi,
    const unsigned short* __restrict__ W2,
    float* __restrict__ off_o, float* __restrict__ mag_o) {
  __shared__ unsigned short S[66 * 256];
  int blk = blockIdx.x;
  int b = blk & 7;
  int rest = blk >> 3;
  int wt = rest & 1;
  int h = rest >> 1;
  int w0 = wt * 64;
  int tid = threadIdx.x;
  int lane = tid & 63;
  int g = tid >> 6;
  int l15 = lane & 15;
  int hi8 = (lane >> 4) * 8;
  const float* xrb = xr + (size_t)b * 64 * HW;
  const float* xib = xi + (size_t)b * 64 * HW;
  int sub = tid & 3;
  int colm = tid >> 2;
  int jm = colm + 1;
  int wm = w0 + colm;
  f32x4 acc[2];
  acc[0] = (f32x4)(0.f);
  acc[1] = (f32x4)(0.f);
#pragma unroll 1
  for (int ty = 0; ty < 3; ++ty) {
    int y = h + ty - 1;
    if ((unsigned)y >= (unsigned)HD) continue;
    __syncthreads();
    int rb = y * WD;
#pragma unroll
    for (int i = 0; i < 24; ++i) {
      int s = sub + i * 4;
      float v0, v1;
      if (s < 32) {
        const float* p = xrb + (size_t)(2 * s) * HW + rb + wm;
        v0 = p[0]; v1 = p[HW];
      } else if (s < 64) {
        const float* p = xib + (size_t)(2 * s - 64) * HW + rb + wm;
        v0 = p[0]; v1 = p[HW];
      } else {
        int c = 2 * s - 128;
        const float* pr = xrb + (size_t)c * HW + rb + wm;
        const float* pi = xib + (size_t)c * HW + rb + wm;
        float a0 = pr[0], a1 = pr[HW];
        float b0 = pi[0], b1 = pi[HW];
        v0 = sqrtf(a0 * a0 + b0 * b0);
        v1 = sqrtf(a1 * a1 + b1 * b1);
      }
      *(unsigned int*)((char*)S + jm * 512 + ((4 * s) ^ ((jm & 7) << 4))) = pkbf(v0, v1);
    }
    if (tid < 192) {
      int j = (tid < 96) ? 0 : 65;
      int s = (tid < 96) ? tid : tid - 96;
      int wg = (j == 0) ? (w0 - 1) : (w0 + 64);
      float v0 = 0.f, v1 = 0.f;
      if ((unsigned)wg < (unsigned)WD) {
        if (s < 32) {
          const float* p = xrb + (size_t)(2 * s) * HW + rb + wg;
          v0 = p[0]; v1 = p[HW];
        } else if (s < 64) {
          const float* p = xib + (size_t)(2 * s - 64) * HW + rb + wg;
          v0 = p[0]; v1 = p[HW];
        } else {
          int c = 2 * s - 128;
          const float* pr = xrb + (size_t)c * HW + rb + wg;
          const float* pi = xib + (size_t)c * HW + rb + wg;
          float a0 = pr[0], a1 = pr[HW];
          float b0 = pi[0], b1 = pi[HW];
          v0 = sqrtf(a0 * a0 + b0 * b0);
          v1 = sqrtf(a1 * a1 + b1 * b1);
        }
      }
      *(unsigned int*)((char*)S + j * 512 + ((4 * s) ^ ((j & 7) << 4))) = pkbf(v0, v1);
    }
    __syncthreads();
#pragma unroll
    for (int tx = 0; tx < 3; ++tx) {
      const unsigned short* wtap = W2 + (size_t)(ty * 3 + tx) * 32 * 192;
      int j = g * 16 + l15 + tx;
      const char* bcol = (const char*)S + j * 512;
      int xo = (j & 7) << 4;
#pragma unroll
      for (int s = 0; s < 6; ++s) {
        s16x8 bf = *(const s16x8*)(bcol + ((s * 64 + hi8 * 2) ^ xo));
#pragma unroll
        for (int mt = 0; mt < 2; ++mt) {
          s16x8 af = *(const s16x8*)(wtap + (mt * 16 + l15) * 192 + s * 32 + hi8);
          acc[mt] = __builtin_amdgcn_mfma_f32_16x16x32_bf16(af, bf, acc[mt], 0, 0, 0);
        }
      }
    }
  }
  int p = h * WD + w0 + g * 16 + l15;
#pragma unroll
  for (int mt = 0; mt < 2; ++mt) {
#pragma unroll
    for (int r = 0; r < 4; ++r) {
      int row = mt * 16 + (lane >> 4) * 4 + r;
      float v = acc[mt][r];
      if (row < 18) off_o[((size_t)(b * 18 + row)) * HW + p] = v;
      else if (row < 27) mag_o[((size_t)(b * 9 + row - 18)) * HW + p] = 1.f / (1.f + expf(-v));
    }
  }
}

__device__ __forceinline__ void gather_tap_f32(
    const float* xbase, char* sbase, int swz, int cbase2,
    float W00, float W01, float W10, float W11, int o0, int o1) {
#pragma unroll
  for (int q = 0; q < 4; ++q) {
    u32x4 wv;
#pragma unroll
    for (int j2 = 0; j2 < 4; ++j2) {
      const float* p0 = xbase + (size_t)(q * 8 + j2 * 2) * HW;
      const float* p1 = p0 + HW;
      f32x2u a0 = *(const f32x2u*)(p0 + o0);
      f32x2u b0 = *(const f32x2u*)(p0 + o1);
      f32x2u a1 = *(const f32x2u*)(p1 + o0);
      f32x2u b1 = *(const f32x2u*)(p1 + o1);
      float v0 = W00 * a0.x + W01 * a0.y + W10 * b0.x + W11 * b0.y;
      float v1 = W00 * a1.x + W01 * a1.y + W10 * b1.x + W11 * b1.y;
      wv[j2] = pkbf(v0, v1);
    }
    *(u32x4*)(sbase + ((cbase2 + q * 16) ^ swz)) = wv;
  }
}

__global__ __launch_bounds__(256, 4) void k_main_f32(
    const float* __restrict__ xr, const float* __restrict__ xi,
    const float* __restrict__ off_i, const float* __restrict__ mag_i,
    const unsigned short* __restrict__ Wc,
    const float* __restrict__ b_real, const float* __restrict__ b_imag,
    float* __restrict__ out) {
  __shared__ unsigned short S[2 * 64 * 128];
  int blk = blockIdx.x;
  int b = blk & 7;
  int rest = blk >> 3;
  int wt = rest & 1;
  int h = rest >> 1;
  int w0 = wt * 64;
  int tid = threadIdx.x;
  int lane = tid & 63;
  int g = tid >> 6;
  int w = w0 + lane;
  int l15 = lane & 15;
  int hi8 = (lane >> 4) * 8;
  int xo = l15 << 4;
  int swz = (lane & 15) << 4;
  const float* xrb = xr + (size_t)b * 64 * HW;
  const float* xib = xi + (size_t)b * 64 * HW;
  int cbase = g * 32;
  const float* xbase = (g < 2) ? (xrb + (size_t)cbase * HW)
                               : (xib + (size_t)(cbase - 64) * HW);
  int ppos = h * WD + w;
  char* sb0 = (char*)S + lane * 256;
  char* sb1 = (char*)S + 16384 + lane * 256;
  f32x4 accR[4], accI[4];
#pragma unroll
  for (int t = 0; t < 4; ++t) {
    accR[t] = (f32x4)(0.f);
    accI[t] = (f32x4)(0.f);
  }
#pragma unroll 1
  for (int ph = 0; ph < 5; ++ph) {
    int kA = ph * 2;
    int kB = kA + 1;
    bool two = (ph < 4);
    float dyA = off_i[((size_t)(b * 18 + 2 * kA)) * HW + ppos];
    float dxA = off_i[((size_t)(b * 18 + 2 * kA + 1)) * HW + ppos];
    float mA  = mag_i[((size_t)(b * 9 + kA)) * HW + ppos];
    float dyB = 0.f, dxB = 0.f, mB = 0.f;
    if (two) {
      dyB = off_i[((size_t)(b * 18 + 2 * kB)) * HW + ppos];
      dxB = off_i[((size_t)(b * 18 + 2 * kB + 1)) * HW + ppos];
      mB  = mag_i[((size_t)(b * 9 + kB)) * HW + ppos];
    }
    __syncthreads();
    {
      float W00, W01, W10, W11; int o0, o1;
      tap_weights(h, w, kA, dyA, dxA, mA, W00, W01, W10, W11, o0, o1);
      gather_tap_f32(xbase, sb0, swz, cbase * 2, W00, W01, W10, W11, o0, o1);
    }
    if (two) {
      float W00, W01, W10, W11; int o0, o1;
      tap_weights(h, w, kB, dyB, dxB, mB, W00, W01, W10, W11, o0, o1);
      gather_tap_f32(xbase, sb1, swz, cbase * 2, W00, W01, W10, W11, o0, o1);
    }
    __syncthreads();
    mfma_tap(Wc, kA, (const char*)S, g, l15, hi8, xo, accR, accI);
    if (two)
      mfma_tap(Wc, kB, (const char*)S + 16384, g, l15, hi8, xo, accR, accI);
  }
  f32x2* outp = (f32x2*)out;
#pragma unroll
  for (int r = 0; r < 4; ++r) {
    int o = g * 16 + (lane >> 4) * 4 + r;
    float br = b_real[o] - b_imag[o];
#pragma unroll
    for (int t = 0; t < 4; ++t) {
      int pe = h * WD + w0 + t * 16 + l15;
      f32x2 v;
      v.x = accR[t][r] + br;
      v.y = accI[t][r] - br;
      __builtin_nontemporal_store(v, &outp[((size_t)(b * 64 + o)) * HW + pe]);
    }
  }
}

// ---------------------------------------------------------------------------
extern "C" void kernel_launch(void* const* d_in, const int* in_sizes, int n_in,
                              void* d_out, int out_size, void* d_ws, size_t ws_size,
                              hipStream_t stream) {
  const float* xr     = (const float*)d_in[0];
  const float* xi     = (const float*)d_in[1];
  const float* w_off  = (const float*)d_in[2];
  const float* w_mag  = (const float*)d_in[3];
  const float* w_real = (const float*)d_in[4];
  const float* w_imag = (const float*)d_in[5];
  const float* b_real = (const float*)d_in[6];
  const float* b_imag = (const float*)d_in[7];
  float* out = (float*)d_out;

  unsigned short* Wc = (unsigned short*)d_ws;        // 147456 bf16
  unsigned short* W2 = Wc + 147456;                  // 55296 bf16
  char* rest = (char*)(W2 + 55296);
  unsigned int* X4 = (unsigned int*)rest;            // 8*32*HW*2 = 8388608 u32
  float* off_ws = (float*)rest;                      // fallback union
  float* mag_ws = off_ws + 2359296;
  const size_t need = (rest - (char*)d_ws) + (size_t)8388608 * 4;
  bool use_x4 = ws_size >= need;

  hipLaunchKernelGGL(k_prepw, dim3(576), dim3(256), 0, stream,
                     w_real, w_imag, Wc);
  hipLaunchKernelGGL(k_prepw2, dim3(216), dim3(256), 0, stream,
                     w_off, w_mag, W2);
  if (use_x4) {
    hipLaunchKernelGGL(k_prepx4, dim3(4096), dim3(256), 0, stream, xr, xi, X4);
    hipLaunchKernelGGL(k_fused, dim3(2048), dim3(256), 0, stream,
                       X4, W2, Wc, b_real, b_imag, out);
  } else {
    hipLaunchKernelGGL(k_offmag_f32, dim3(2048), dim3(256), 0, stream,
                       xr, xi, W2, off_ws, mag_ws);
    hipLaunchKernelGGL(k_main_f32, dim3(2048), dim3(256), 0, stream,
                       xr, xi, off_ws, mag_ws, Wc, b_real, b_imag, out);
  }
}

// Round 16
// 292.763 us; speedup vs baseline: 1.8490x; 1.1255x over previous
//
#include <hip/hip_runtime.h>
#include <math.h>

#define HD 128
#define WD 128
#define HW (HD*WD)

typedef __attribute__((ext_vector_type(8))) short s16x8;     // 8 bf16 (4 VGPRs)
typedef __attribute__((ext_vector_type(4))) float f32x4;     // MFMA acc
typedef __attribute__((ext_vector_type(4))) unsigned int u32x4;
typedef __attribute__((ext_vector_type(2))) float f32x2;
typedef f32x2 __attribute__((aligned(4))) f32x2u;
typedef u32x4 __attribute__((aligned(4))) u32x4u;
typedef __attribute__((ext_vector_type(2))) unsigned int u32x2;
typedef u32x2 __attribute__((aligned(4))) u32x2u;

__device__ inline unsigned int pkbf(float a, float b) {
  unsigned int ua = __builtin_bit_cast(unsigned int, a);
  unsigned int ub = __builtin_bit_cast(unsigned int, b);
  ua = (ua + 0x7fffu + ((ua >> 16) & 1u)) >> 16;
  ub = (ub + 0x7fffu + ((ub >> 16) & 1u)) >> 16;
  return ua | (ub << 16);
}
__device__ __forceinline__ float blo(unsigned int u) {
  return __builtin_bit_cast(float, u << 16);
}
__device__ __forceinline__ float bhi(unsigned int u) {
  return __builtin_bit_cast(float, u & 0xffff0000u);
}

// ---------------------------------------------------------------------------
// Kernel 0a: Wcomb[9][128][128] bf16 for the main contraction.
// ---------------------------------------------------------------------------
__global__ __launch_bounds__(256) void k_prepw(
    const float* __restrict__ wr, const float* __restrict__ wi,
    unsigned short* __restrict__ wc) {
  int t = blockIdx.x * 256 + threadIdx.x;
  if (t >= 9 * 128 * 128) return;
  int c = t & 127;
  int r = (t >> 7) & 127;
  int k = t >> 14;
  float v;
  if (r < 64) v = (c < 64) ? wr[(r * 64 + c) * 9 + k] : -wi[(r * 64 + c - 64) * 9 + k];
  else {
    int r2 = r - 64;
    v = (c < 64) ? wi[(r2 * 64 + c) * 9 + k] : -wr[(r2 * 64 + c - 64) * 9 + k];
  }
  unsigned int u = __builtin_bit_cast(unsigned int, v);
  u = (u + 0x7fffu + ((u >> 16) & 1u)) >> 16;
  wc[t] = (unsigned short)u;
}

// ---------------------------------------------------------------------------
// Kernel 0b: W2[9 taps][32 rows][192 chans] bf16 for the off/mag GEMM.
// ---------------------------------------------------------------------------
__global__ __launch_bounds__(256) void k_prepw2(
    const float* __restrict__ w_off, const float* __restrict__ w_mag,
    unsigned short* __restrict__ w2) {
  int t = blockIdx.x * 256 + threadIdx.x;   // 9*32*192 = 55296 exactly
  int c = t % 192;
  int r = (t / 192) % 32;
  int k = t / (192 * 32);
  float v = 0.f;
  if (r < 18 && c < 128) v = w_off[((size_t)r * 128 + c) * 9 + k];
  else if (r >= 18 && r < 27 && c >= 128) v = w_mag[((size_t)(r - 18) * 64 + (c - 128)) * 9 + k];
  unsigned int u = __builtin_bit_cast(unsigned int, v);
  u = (u + 0x7fffu + ((u >> 16) & 1u)) >> 16;
  w2[t] = (unsigned short)u;
}

// ---------------------------------------------------------------------------
// Kernel 0c: coalesced X4 pack (32 groups/batch — proven L2-friendly layout).
//   grp 0..15: xr chans 4g..4g+3;  grp 16..31: xi chans.
// u32 index ((b*32+grp)*HW + pix)*2 + half; half0 = chans(0,1), half1 = (2,3).
// ---------------------------------------------------------------------------
__global__ __launch_bounds__(256) void k_prepx4(
    const float* __restrict__ xr, const float* __restrict__ xi,
    unsigned int* __restrict__ X4) {
  int b = blockIdx.x & 7;
  int idx = (blockIdx.x >> 3) * 256 + threadIdx.x;   // 0..131071
  int pix4 = idx & 4095;
  int grp = idx >> 12;                               // 0..31
  const float* src = (grp < 16) ? (xr + ((size_t)b * 64 + 4 * grp) * HW)
                                : (xi + ((size_t)b * 64 + 4 * (grp - 16)) * HW);
  const float* p = src + pix4 * 4;
  f32x4 c0 = *(const f32x4*)(p);
  f32x4 c1 = *(const f32x4*)(p + HW);
  f32x4 c2 = *(const f32x4*)(p + 2 * HW);
  f32x4 c3 = *(const f32x4*)(p + 3 * HW);
  u32x4 o0, o1;
#pragma unroll
  for (int j = 0; j < 2; ++j) {
    o0[2 * j] = pkbf(c0[j], c1[j]);
    o0[2 * j + 1] = pkbf(c2[j], c3[j]);
    o1[2 * j] = pkbf(c0[j + 2], c1[j + 2]);
    o1[2 * j + 1] = pkbf(c2[j + 2], c3[j + 2]);
  }
  unsigned int* dst = X4 + ((size_t)(b * 32 + grp) * HW + pix4 * 4) * 2;
  *(u32x4*)(dst) = o0;
  *(u32x4*)(dst + 4) = o1;
}

// ---------------------------------------------------------------------------
// helpers
// ---------------------------------------------------------------------------
__device__ __forceinline__ void tap_weights(
    int h, int w, int k, float dy, float dx, float m,
    float& W00, float& W01, float& W10, float& W11, int& o0, int& o1) {
  float py = (float)(h - 1 + k / 3) + dy;
  float px = (float)(w - 1 + k % 3) + dx;
  float y0f = floorf(py), x0f = floorf(px);
  float wy = py - y0f, wx = px - x0f;
  int y0 = (int)y0f, x0 = (int)x0f;

  int xl = x0 < 0 ? 0 : (x0 > WD - 2 ? WD - 2 : x0);
  float wl, wr;
  if (x0 < 0) { wl = (x0 == -1) ? wx : 0.f; wr = 0.f; }
  else if (x0 > WD - 2) { wl = 0.f; wr = (x0 == WD - 1) ? (1.f - wx) : 0.f; }
  else { wl = 1.f - wx; wr = wx; }

  int y1 = y0 + 1;
  int yc0 = y0 < 0 ? 0 : (y0 > HD - 1 ? HD - 1 : y0);
  int yc1 = y1 < 0 ? 0 : (y1 > HD - 1 ? HD - 1 : y1);
  float cy0 = ((unsigned)y0 < (unsigned)HD) ? (1.f - wy) * m : 0.f;
  float cy1 = ((unsigned)y1 < (unsigned)HD) ? wy * m : 0.f;

  W00 = cy0 * wl; W01 = cy0 * wr;
  W10 = cy1 * wl; W11 = cy1 * wr;
  o0 = yc0 * WD + xl;
  o1 = yc1 * WD + xl;
}

// load one q-slab (8 chans x 2 corners) of a tap
__device__ __forceinline__ void load_q(
    const unsigned int* xq, int q, int o0, int o1,
    u32x4& A0, u32x4& B0, u32x4& A1, u32x4& B1) {
  const unsigned int* pg0 = xq + (size_t)(q * 2) * (2 * HW);
  const unsigned int* pg1 = pg0 + 2 * HW;
  A0 = *(const u32x4u*)(pg0 + 2 * o0);
  B0 = *(const u32x4u*)(pg0 + 2 * o1);
  A1 = *(const u32x4u*)(pg1 + 2 * o0);
  B1 = *(const u32x4u*)(pg1 + 2 * o1);
}

// bilinear-combine one q-slab and write 16B to swizzled LDS
__device__ __forceinline__ void write_q(
    char* sb, int swz, int cbase2, int q,
    float W00, float W01, float W10, float W11,
    u32x4 A0, u32x4 B0, u32x4 A1, u32x4 B1) {
  float c0 = W00 * blo(A0[0]) + W01 * blo(A0[2]) + W10 * blo(B0[0]) + W11 * blo(B0[2]);
  float c1 = W00 * bhi(A0[0]) + W01 * bhi(A0[2]) + W10 * bhi(B0[0]) + W11 * bhi(B0[2]);
  float c2 = W00 * blo(A0[1]) + W01 * blo(A0[3]) + W10 * blo(B0[1]) + W11 * blo(B0[3]);
  float c3 = W00 * bhi(A0[1]) + W01 * bhi(A0[3]) + W10 * bhi(B0[1]) + W11 * bhi(B0[3]);
  float c4 = W00 * blo(A1[0]) + W01 * blo(A1[2]) + W10 * blo(B1[0]) + W11 * blo(B1[2]);
  float c5 = W00 * bhi(A1[0]) + W01 * bhi(A1[2]) + W10 * bhi(B1[0]) + W11 * bhi(B1[2]);
  float c6 = W00 * blo(A1[1]) + W01 * blo(A1[3]) + W10 * blo(B1[1]) + W11 * blo(B1[3]);
  float c7 = W00 * bhi(A1[1]) + W01 * bhi(A1[3]) + W10 * bhi(B1[1]) + W11 * bhi(B1[3]);
  u32x4 wv;
  wv[0] = pkbf(c0, c1);
  wv[1] = pkbf(c2, c3);
  wv[2] = pkbf(c4, c5);
  wv[3] = pkbf(c6, c7);
  *(u32x4*)(sb + ((cbase2 + q * 16) ^ swz)) = wv;
}

// gather BOTH taps of a phase, interleaved q-by-q: 8 loads in flight
// (tap A slab q + tap B slab q) before each pair of combines.
__device__ __forceinline__ void gather_two(
    const unsigned int* xq, char* sbA, char* sbB, int swz, int cbase2,
    float A00, float A01, float A10, float A11, int a0, int a1,
    float B00, float B01, float B10, float B11, int b0, int b1) {
#pragma unroll
  for (int q = 0; q < 4; ++q) {
    u32x4 Pa0, Pb0, Pa1, Pb1, Qa0, Qb0, Qa1, Qb1;
    load_q(xq, q, a0, a1, Pa0, Pb0, Pa1, Pb1);
    load_q(xq, q, b0, b1, Qa0, Qb0, Qa1, Qb1);
    write_q(sbA, swz, cbase2, q, A00, A01, A10, A11, Pa0, Pb0, Pa1, Pb1);
    write_q(sbB, swz, cbase2, q, B00, B01, B10, B11, Qa0, Qb0, Qa1, Qb1);
  }
}

// single-tap gather with q-pair load batching (8 loads in flight)
__device__ __forceinline__ void gather_one(
    const unsigned int* xq, char* sb, int swz, int cbase2,
    float W00, float W01, float W10, float W11, int o0, int o1) {
#pragma unroll
  for (int qp = 0; qp < 2; ++qp) {
    u32x4 Pa0, Pb0, Pa1, Pb1, Qa0, Qb0, Qa1, Qb1;
    load_q(xq, 2 * qp, o0, o1, Pa0, Pb0, Pa1, Pb1);
    load_q(xq, 2 * qp + 1, o0, o1, Qa0, Qb0, Qa1, Qb1);
    write_q(sb, swz, cbase2, 2 * qp, W00, W01, W10, W11, Pa0, Pb0, Pa1, Pb1);
    write_q(sb, swz, cbase2, 2 * qp + 1, W00, W01, W10, W11, Qa0, Qb0, Qa1, Qb1);
  }
}

__device__ __forceinline__ void mfma_tap(
    const unsigned short* Wc, int k, const char* stap,
    int g, int l15, int hi8, int xo, f32x4* accR, f32x4* accI) {
  const unsigned short* wa = Wc + (size_t)k * 16384 + (g * 16 + l15) * 128 + hi8;
  s16x8 aR[4], aI[4];
#pragma unroll
  for (int s = 0; s < 4; ++s) {
    aR[s] = *(const s16x8*)(wa + s * 32);
    aI[s] = *(const s16x8*)(wa + 64 * 128 + s * 32);
  }
  __builtin_amdgcn_s_setprio(1);
#pragma unroll
  for (int t = 0; t < 4; ++t) {
    const char* brow = stap + (t * 16 + l15) * 256;
#pragma unroll
    for (int s = 0; s < 4; ++s) {
      s16x8 bf = *(const s16x8*)(brow + ((s * 64 + (hi8 << 1)) ^ xo));
      accR[t] = __builtin_amdgcn_mfma_f32_16x16x32_bf16(aR[s], bf, accR[t], 0, 0, 0);
      accI[t] = __builtin_amdgcn_mfma_f32_16x16x32_bf16(aI[s], bf, accI[t], 0, 0, 0);
    }
  }
  __builtin_amdgcn_s_setprio(0);
}

// load one 4-chan group (u32x2) for 192-space pair-index g2 (mag on the fly)
__device__ __forceinline__ u32x2 stage_pair(
    const unsigned int* __restrict__ X4, int b, int g2, int pix) {
  if (g2 < 32) {
    return *(const u32x2u*)&X4[((size_t)(b * 32 + g2) * HW + pix) * 2];
  }
  int gm = g2 - 32;
  u32x2 A = *(const u32x2u*)&X4[((size_t)(b * 32 + gm) * HW + pix) * 2];
  u32x2 B = *(const u32x2u*)&X4[((size_t)(b * 32 + 16 + gm) * HW + pix) * 2];
  u32x2 r;
  r.x = pkbf(sqrtf(blo(A.x) * blo(A.x) + blo(B.x) * blo(B.x)),
             sqrtf(bhi(A.x) * bhi(A.x) + bhi(B.x) * bhi(B.x)));
  r.y = pkbf(sqrtf(blo(A.y) * blo(A.y) + blo(B.y) * blo(B.y)),
             sqrtf(bhi(A.y) * bhi(A.y) + bhi(B.y) * bhi(B.y)));
  return r;
}

// ---------------------------------------------------------------------------
// Fused kernel (round-12 proven 291µs structure; ONLY change: phase-B
// gathers interleave the two taps' loads q-by-q for 2x memory-level
// parallelism — 8 loads in flight instead of 4).
// ---------------------------------------------------------------------------
__global__ __launch_bounds__(256, 4) void k_fused(
    const unsigned int* __restrict__ X4,
    const unsigned short* __restrict__ W2,
    const unsigned short* __restrict__ Wc,
    const float* __restrict__ b_real, const float* __restrict__ b_imag,
    float* __restrict__ out) {
  __shared__ __align__(16) char LB[33792 + 6912];
  float* om = (float*)(LB + 33792);                  // om[27][64]

  int blk = blockIdx.x;
  int b = blk & 7;                 // XCD-affine
  int rest = blk >> 3;
  int wt = rest & 1;
  int h = rest >> 1;
  int w0 = wt * 64;

  int tid = threadIdx.x;
  int lane = tid & 63;
  int g = tid >> 6;
  int l15 = lane & 15;
  int hi8 = (lane >> 4) * 8;

  // ================= phase A =================
  {
    int sub = tid & 3;
    int colm = tid >> 2;
    int jm = colm + 1;
    int wm = w0 + colm;

    f32x4 acc[2];
    acc[0] = (f32x4)(0.f);
    acc[1] = (f32x4)(0.f);

#pragma unroll 1
    for (int ty = 0; ty < 3; ++ty) {
      int y = h + ty - 1;
      if ((unsigned)y >= (unsigned)HD) continue;
      __syncthreads();
      int rb = y * WD;

#pragma unroll
      for (int i = 0; i < 12; ++i) {
        int g2 = sub + i * 4;                        // 0..47
        u32x2 pk2 = stage_pair(X4, b, g2, rb + wm);
        *(u32x2*)(LB + jm * 512 + ((8 * g2) ^ ((jm & 7) << 4))) = pk2;
      }
      if (tid < 96) {
        int j = (tid < 48) ? 0 : 65;
        int g2 = (tid < 48) ? tid : tid - 48;
        int wg = (j == 0) ? (w0 - 1) : (w0 + 64);
        u32x2 pk2;
        pk2.x = 0u; pk2.y = 0u;
        if ((unsigned)wg < (unsigned)WD) pk2 = stage_pair(X4, b, g2, rb + wg);
        *(u32x2*)(LB + j * 512 + ((8 * g2) ^ ((j & 7) << 4))) = pk2;
      }
      __syncthreads();

#pragma unroll
      for (int tx = 0; tx < 3; ++tx) {
        const unsigned short* wtap = W2 + (size_t)(ty * 3 + tx) * 32 * 192;
        int j = g * 16 + l15 + tx;
        const char* bcol = LB + j * 512;
        int xo2 = (j & 7) << 4;
#pragma unroll
        for (int s = 0; s < 6; ++s) {
          s16x8 bf = *(const s16x8*)(bcol + ((s * 64 + hi8 * 2) ^ xo2));
#pragma unroll
          for (int mt = 0; mt < 2; ++mt) {
            s16x8 af = *(const s16x8*)(wtap + (mt * 16 + l15) * 192 + s * 32 + hi8);
            acc[mt] = __builtin_amdgcn_mfma_f32_16x16x32_bf16(af, bf, acc[mt], 0, 0, 0);
          }
        }
      }
    }

    // results -> om LDS (sigmoid on mag rows)
    __syncthreads();
    int col = g * 16 + l15;
#pragma unroll
    for (int mt = 0; mt < 2; ++mt) {
#pragma unroll
      for (int r = 0; r < 4; ++r) {
        int row = mt * 16 + (lane >> 4) * 4 + r;
        float v = acc[mt][r];
        if (row < 18) om[row * 64 + col] = v;
        else if (row < 27) om[row * 64 + col] = 1.f / (1.f + expf(-v));
      }
    }
    __syncthreads();
  }

  // ================= phase B =================
  int w = w0 + lane;
  int xo = l15 << 4;
  int swz = (lane & 15) << 4;
  int cbase = g * 32;
  const unsigned int* xq = X4 + (size_t)(b * 32 + g * 8) * (2 * HW);
  char* sb0 = LB + lane * 256;
  char* sb1 = LB + 16384 + lane * 256;

  f32x4 accR[4], accI[4];
#pragma unroll
  for (int t = 0; t < 4; ++t) {
    accR[t] = (f32x4)(0.f);
    accI[t] = (f32x4)(0.f);
  }

#pragma unroll 1
  for (int ph = 0; ph < 5; ++ph) {
    int kA = ph * 2;
    int kB = kA + 1;
    bool two = (ph < 4);

    float dyA = om[(2 * kA) * 64 + lane];
    float dxA = om[(2 * kA + 1) * 64 + lane];
    float mA  = om[(18 + kA) * 64 + lane];
    float dyB = 0.f, dxB = 0.f, mB = 0.f;
    if (two) {
      dyB = om[(2 * kB) * 64 + lane];
      dxB = om[(2 * kB + 1) * 64 + lane];
      mB  = om[(18 + kB) * 64 + lane];
    }

    __syncthreads();   // prev MFMA phase done reading tap buffers

    if (two) {
      float A00, A01, A10, A11, B00, B01, B10, B11;
      int a0, a1, b0c, b1c;
      tap_weights(h, w, kA, dyA, dxA, mA, A00, A01, A10, A11, a0, a1);
      tap_weights(h, w, kB, dyB, dxB, mB, B00, B01, B10, B11, b0c, b1c);
      gather_two(xq, sb0, sb1, swz, cbase * 2,
                 A00, A01, A10, A11, a0, a1,
                 B00, B01, B10, B11, b0c, b1c);
    } else {
      float W00, W01, W10, W11;
      int o0, o1;
      tap_weights(h, w, kA, dyA, dxA, mA, W00, W01, W10, W11, o0, o1);
      gather_one(xq, sb0, swz, cbase * 2, W00, W01, W10, W11, o0, o1);
    }
    __syncthreads();

    mfma_tap(Wc, kA, LB, g, l15, hi8, xo, accR, accI);
    if (two)
      mfma_tap(Wc, kB, LB + 16384, g, l15, hi8, xo, accR, accI);
  }

  // epilogue: bias + coalesced nontemporal f32x2 stores
  f32x2* outp = (f32x2*)out;
#pragma unroll
  for (int r = 0; r < 4; ++r) {
    int o = g * 16 + (lane >> 4) * 4 + r;
    float br = b_real[o] - b_imag[o];
#pragma unroll
    for (int t = 0; t < 4; ++t) {
      int pe = h * WD + w0 + t * 16 + l15;
      f32x2 v;
      v.x = accR[t][r] + br;
      v.y = accI[t][r] - br;
      __builtin_nontemporal_store(v, &outp[((size_t)(b * 64 + o)) * HW + pe]);
    }
  }
}

// ---------------------------------------------------------------------------
// Fallback path (ws too small for X4): f32 kernels (round-11 proven).
// ---------------------------------------------------------------------------
__global__ __launch_bounds__(256) void k_offmag_f32(
    const float* __restrict__ xr, const float* __restrict__ xi,
    const unsigned short* __restrict__ W2,
    float* __restrict__ off_o, float* __restrict__ mag_o) {
  __shared__ unsigned short S[66 * 256];
  int blk = blockIdx.x;
  int b = blk & 7;
  int rest = blk >> 3;
  int wt = rest & 1;
  int h = rest >> 1;
  int w0 = wt * 64;
  int tid = threadIdx.x;
  int lane = tid & 63;
  int g = tid >> 6;
  int l15 = lane & 15;
  int hi8 = (lane >> 4) * 8;
  const float* xrb = xr + (size_t)b * 64 * HW;
  const float* xib = xi + (size_t)b * 64 * HW;
  int sub = tid & 3;
  int colm = tid >> 2;
  int jm = colm + 1;
  int wm = w0 + colm;
  f32x4 acc[2];
  acc[0] = (f32x4)(0.f);
  acc[1] = (f32x4)(0.f);
#pragma unroll 1
  for (int ty = 0; ty < 3; ++ty) {
    int y = h + ty - 1;
    if ((unsigned)y >= (unsigned)HD) continue;
    __syncthreads();
    int rb = y * WD;
#pragma unroll
    for (int i = 0; i < 24; ++i) {
      int s = sub + i * 4;
      float v0, v1;
      if (s < 32) {
        const float* p = xrb + (size_t)(2 * s) * HW + rb + wm;
        v0 = p[0]; v1 = p[HW];
      } else if (s < 64) {
        const float* p = xib + (size_t)(2 * s - 64) * HW + rb + wm;
        v0 = p[0]; v1 = p[HW];
      } else {
        int c = 2 * s - 128;
        const float* pr = xrb + (size_t)c * HW + rb + wm;
        const float* pi = xib + (size_t)c * HW + rb + wm;
        float a0 = pr[0], a1 = pr[HW];
        float b0 = pi[0], b1 = pi[HW];
        v0 = sqrtf(a0 * a0 + b0 * b0);
        v1 = sqrtf(a1 * a1 + b1 * b1);
      }
      *(unsigned int*)((char*)S + jm * 512 + ((4 * s) ^ ((jm & 7) << 4))) = pkbf(v0, v1);
    }
    if (tid < 192) {
      int j = (tid < 96) ? 0 : 65;
      int s = (tid < 96) ? tid : tid - 96;
      int wg = (j == 0) ? (w0 - 1) : (w0 + 64);
      float v0 = 0.f, v1 = 0.f;
      if ((unsigned)wg < (unsigned)WD) {
        if (s < 32) {
          const float* p = xrb + (size_t)(2 * s) * HW + rb + wg;
          v0 = p[0]; v1 = p[HW];
        } else if (s < 64) {
          const float* p = xib + (size_t)(2 * s - 64) * HW + rb + wg;
          v0 = p[0]; v1 = p[HW];
        } else {
          int c = 2 * s - 128;
          const float* pr = xrb + (size_t)c * HW + rb + wg;
          const float* pi = xib + (size_t)c * HW + rb + wg;
          float a0 = pr[0], a1 = pr[HW];
          float b0 = pi[0], b1 = pi[HW];
          v0 = sqrtf(a0 * a0 + b0 * b0);
          v1 = sqrtf(a1 * a1 + b1 * b1);
        }
      }
      *(unsigned int*)((char*)S + j * 512 + ((4 * s) ^ ((j & 7) << 4))) = pkbf(v0, v1);
    }
    __syncthreads();
#pragma unroll
    for (int tx = 0; tx < 3; ++tx) {
      const unsigned short* wtap = W2 + (size_t)(ty * 3 + tx) * 32 * 192;
      int j = g * 16 + l15 + tx;
      const char* bcol = (const char*)S + j * 512;
      int xo = (j & 7) << 4;
#pragma unroll
      for (int s = 0; s < 6; ++s) {
        s16x8 bf = *(const s16x8*)(bcol + ((s * 64 + hi8 * 2) ^ xo));
#pragma unroll
        for (int mt = 0; mt < 2; ++mt) {
          s16x8 af = *(const s16x8*)(wtap + (mt * 16 + l15) * 192 + s * 32 + hi8);
          acc[mt] = __builtin_amdgcn_mfma_f32_16x16x32_bf16(af, bf, acc[mt], 0, 0, 0);
        }
      }
    }
  }
  int p = h * WD + w0 + g * 16 + l15;
#pragma unroll
  for (int mt = 0; mt < 2; ++mt) {
#pragma unroll
    for (int r = 0; r < 4; ++r) {
      int row = mt * 16 + (lane >> 4) * 4 + r;
      float v = acc[mt][r];
      if (row < 18) off_o[((size_t)(b * 18 + row)) * HW + p] = v;
      else if (row < 27) mag_o[((size_t)(b * 9 + row - 18)) * HW + p] = 1.f / (1.f + expf(-v));
    }
  }
}

__device__ __forceinline__ void gather_tap_f32(
    const float* xbase, char* sbase, int swz, int cbase2,
    float W00, float W01, float W10, float W11, int o0, int o1) {
#pragma unroll
  for (int q = 0; q < 4; ++q) {
    u32x4 wv;
#pragma unroll
    for (int j2 = 0; j2 < 4; ++j2) {
      const float* p0 = xbase + (size_t)(q * 8 + j2 * 2) * HW;
      const float* p1 = p0 + HW;
      f32x2u a0 = *(const f32x2u*)(p0 + o0);
      f32x2u b0 = *(const f32x2u*)(p0 + o1);
      f32x2u a1 = *(const f32x2u*)(p1 + o0);
      f32x2u b1 = *(const f32x2u*)(p1 + o1);
      float v0 = W00 * a0.x + W01 * a0.y + W10 * b0.x + W11 * b0.y;
      float v1 = W00 * a1.x + W01 * a1.y + W10 * b1.x + W11 * b1.y;
      wv[j2] = pkbf(v0, v1);
    }
    *(u32x4*)(sbase + ((cbase2 + q * 16) ^ swz)) = wv;
  }
}

__global__ __launch_bounds__(256, 4) void k_main_f32(
    const float* __restrict__ xr, const float* __restrict__ xi,
    const float* __restrict__ off_i, const float* __restrict__ mag_i,
    const unsigned short* __restrict__ Wc,
    const float* __restrict__ b_real, const float* __restrict__ b_imag,
    float* __restrict__ out) {
  __shared__ unsigned short S[2 * 64 * 128];
  int blk = blockIdx.x;
  int b = blk & 7;
  int rest = blk >> 3;
  int wt = rest & 1;
  int h = rest >> 1;
  int w0 = wt * 64;
  int tid = threadIdx.x;
  int lane = tid & 63;
  int g = tid >> 6;
  int w = w0 + lane;
  int l15 = lane & 15;
  int hi8 = (lane >> 4) * 8;
  int xo = l15 << 4;
  int swz = (lane & 15) << 4;
  const float* xrb = xr + (size_t)b * 64 * HW;
  const float* xib = xi + (size_t)b * 64 * HW;
  int cbase = g * 32;
  const float* xbase = (g < 2) ? (xrb + (size_t)cbase * HW)
                               : (xib + (size_t)(cbase - 64) * HW);
  int ppos = h * WD + w;
  char* sb0 = (char*)S + lane * 256;
  char* sb1 = (char*)S + 16384 + lane * 256;
  f32x4 accR[4], accI[4];
#pragma unroll
  for (int t = 0; t < 4; ++t) {
    accR[t] = (f32x4)(0.f);
    accI[t] = (f32x4)(0.f);
  }
#pragma unroll 1
  for (int ph = 0; ph < 5; ++ph) {
    int kA = ph * 2;
    int kB = kA + 1;
    bool two = (ph < 4);
    float dyA = off_i[((size_t)(b * 18 + 2 * kA)) * HW + ppos];
    float dxA = off_i[((size_t)(b * 18 + 2 * kA + 1)) * HW + ppos];
    float mA  = mag_i[((size_t)(b * 9 + kA)) * HW + ppos];
    float dyB = 0.f, dxB = 0.f, mB = 0.f;
    if (two) {
      dyB = off_i[((size_t)(b * 18 + 2 * kB)) * HW + ppos];
      dxB = off_i[((size_t)(b * 18 + 2 * kB + 1)) * HW + ppos];
      mB  = mag_i[((size_t)(b * 9 + kB)) * HW + ppos];
    }
    __syncthreads();
    {
      float W00, W01, W10, W11; int o0, o1;
      tap_weights(h, w, kA, dyA, dxA, mA, W00, W01, W10, W11, o0, o1);
      gather_tap_f32(xbase, sb0, swz, cbase * 2, W00, W01, W10, W11, o0, o1);
    }
    if (two) {
      float W00, W01, W10, W11; int o0, o1;
      tap_weights(h, w, kB, dyB, dxB, mB, W00, W01, W10, W11, o0, o1);
      gather_tap_f32(xbase, sb1, swz, cbase * 2, W00, W01, W10, W11, o0, o1);
    }
    __syncthreads();
    mfma_tap(Wc, kA, (const char*)S, g, l15, hi8, xo, accR, accI);
    if (two)
      mfma_tap(Wc, kB, (const char*)S + 16384, g, l15, hi8, xo, accR, accI);
  }
  f32x2* outp = (f32x2*)out;
#pragma unroll
  for (int r = 0; r < 4; ++r) {
    int o = g * 16 + (lane >> 4) * 4 + r;
    float br = b_real[o] - b_imag[o];
#pragma unroll
    for (int t = 0; t < 4; ++t) {
      int pe = h * WD + w0 + t * 16 + l15;
      f32x2 v;
      v.x = accR[t][r] + br;
      v.y = accI[t][r] - br;
      __builtin_nontemporal_store(v, &outp[((size_t)(b * 64 + o)) * HW + pe]);
    }
  }
}

// ---------------------------------------------------------------------------
extern "C" void kernel_launch(void* const* d_in, const int* in_sizes, int n_in,
                              void* d_out, int out_size, void* d_ws, size_t ws_size,
                              hipStream_t stream) {
  const float* xr     = (const float*)d_in[0];
  const float* xi     = (const float*)d_in[1];
  const float* w_off  = (const float*)d_in[2];
  const float* w_mag  = (const float*)d_in[3];
  const float* w_real = (const float*)d_in[4];
  const float* w_imag = (const float*)d_in[5];
  const float* b_real = (const float*)d_in[6];
  const float* b_imag = (const float*)d_in[7];
  float* out = (float*)d_out;

  unsigned short* Wc = (unsigned short*)d_ws;        // 147456 bf16
  unsigned short* W2 = Wc + 147456;                  // 55296 bf16
  char* rest = (char*)(W2 + 55296);
  unsigned int* X4 = (unsigned int*)rest;            // 8*32*HW*2 = 8388608 u32
  float* off_ws = (float*)rest;                      // fallback union
  float* mag_ws = off_ws + 2359296;
  const size_t need = (rest - (char*)d_ws) + (size_t)8388608 * 4;
  bool use_x4 = ws_size >= need;

  hipLaunchKernelGGL(k_prepw, dim3(576), dim3(256), 0, stream,
                     w_real, w_imag, Wc);
  hipLaunchKernelGGL(k_prepw2, dim3(216), dim3(256), 0, stream,
                     w_off, w_mag, W2);
  if (use_x4) {
    hipLaunchKernelGGL(k_prepx4, dim3(4096), dim3(256), 0, stream, xr, xi, X4);
    hipLaunchKernelGGL(k_fused, dim3(2048), dim3(256), 0, stream,
                       X4, W2, Wc, b_real, b_imag, out);
  } else {
    hipLaunchKernelGGL(k_offmag_f32, dim3(2048), dim3(256), 0, stream,
                       xr, xi, W2, off_ws, mag_ws);
    hipLaunchKernelGGL(k_main_f32, dim3(2048), dim3(256), 0, stream,
                       xr, xi, off_ws, mag_ws, Wc, b_real, b_imag, out);
  }
}